// Round 6
// baseline (91.059 us; speedup 1.0000x reference)
//
#include <hip/hip_runtime.h>
#include <stdint.h>

// Problem constants
#define N_ANCHOR 2048
#define DIM 128
#define NEG_PER 15
#define NZ 32768                    // 2048*16 candidate rows
#define NROWS (N_ANCHOR + NZ)       // 34816
#define INV_TEMP 3.3333333333333335f
#define LOG2E 1.4426950408889634f
#define LN2 0.6931471805599453f
#define TOTAL_ELEMS 67108864.0f
#define A_PRESCALE (INV_TEMP * LOG2E)   // folded into anchor normalization

#define BM 128                      // rows per block (4 waves x 32)
#define CPB 256                     // cols per block
#define NT (CPB / 32)               // 8 B-tiles of 32 cols
#define RB (N_ANCHOR / BM)          // 16
#define CG (NZ / CPB)               // 128
#define NBLK (RB * CG)              // 2048  -> 8 blocks/CU nominal

using bf16x8 = __attribute__((ext_vector_type(8))) __bf16;
using f32x4  = __attribute__((ext_vector_type(4))) float;

// ---------- helpers ----------
static __device__ __forceinline__ unsigned short f2bf(float f) {
  union { float f; unsigned u; } v; v.f = f;
  unsigned r = v.u + 0x7FFF + ((v.u >> 16) & 1);   // round-to-nearest-even
  return (unsigned short)(r >> 16);
}

static __device__ __forceinline__ void gload_lds16(const void* g, void* l) {
  __builtin_amdgcn_global_load_lds(
      (const __attribute__((address_space(1))) void*)g,
      (__attribute__((address_space(3))) void*)l, 16, 0, 0);
}

// ---------- kernel 1: L2-normalize rows, cast to bf16 ----------
__global__ __launch_bounds__(256) void norm_kernel(
    const float* __restrict__ anchor, const float* __restrict__ pos,
    const float* __restrict__ neg, unsigned short* __restrict__ a_bf,
    unsigned short* __restrict__ z_bf) {
  int row = blockIdx.x * 8 + (threadIdx.x >> 5);
  int l32 = threadIdx.x & 31;
  const float* src;
  unsigned short* dst;
  float pre;
  if (row < N_ANCHOR) {
    src = anchor + row * DIM;
    dst = a_bf + row * DIM;
    pre = A_PRESCALE;
  } else {
    int rz = row - N_ANCHOR;
    int j = rz >> 4, k = rz & 15;
    src = (k == 0) ? (pos + j * DIM) : (neg + (j * NEG_PER + (k - 1)) * DIM);
    dst = z_bf + rz * DIM;
    pre = 1.0f;
  }
  float4 v = ((const float4*)src)[l32];
  float s = v.x * v.x + v.y * v.y + v.z * v.z + v.w * v.w;
  #pragma unroll
  for (int o = 16; o >= 1; o >>= 1) s += __shfl_xor(s, o, 32);
  float scale = pre / fmaxf(sqrtf(s), 1e-12f);
  ushort4 o4;
  o4.x = f2bf(v.x * scale); o4.y = f2bf(v.y * scale);
  o4.z = f2bf(v.z * scale); o4.w = f2bf(v.w * scale);
  ((ushort4*)dst)[l32] = o4;
}

// ---------- kernel 2: fused GEMM + loss ----------
// R5 post-mortem: structure was fine but 512 blocks = only 8 waves/CU (25%
// occupancy cap) -> latency-bound at 43.6us regardless of pipeline. R6:
// 2048 blocks (BM=128: 4 waves x 32 rows, af[2][4]=32 VGPR; CPB=256) for
// 4-5 resident blocks/CU = 16-20 waves/CU. Same counted-vmcnt double-buffer.
__global__ __launch_bounds__(256) void gemm_loss_kernel(
    const unsigned short* __restrict__ a_bf,
    const unsigned short* __restrict__ z_bf,
    float* __restrict__ partial, unsigned* __restrict__ counter,
    float* __restrict__ out) {
  __shared__ __align__(16) unsigned short Bs[2][512 * 8];   // 2 x 8 KB
  __shared__ float red[4];
  __shared__ int lastflag;

  const int t    = threadIdx.x;
  const int bid  = blockIdx.x;
  const int rb   = bid / CG;
  const int cgi  = bid % CG;
  const int wave = t >> 6;
  const int lane = t & 63;
  const int g    = lane >> 4;
  const int r16  = lane & 15;
  const int c0   = cgi * CPB;

  // B stage source pointers (fragment order, verified R2/R5): LDS slot
  // s = it*256 + t holds B[col j*16+rr][kchunk ks*4+gg],
  // j=s>>8, ks=(s>>6)&3, gg=(s>>4)&3, rr=s&15
  const unsigned short* pB[2];
  #pragma unroll
  for (int it = 0; it < 2; ++it) {
    int s = it * 256 + t;
    int j = s >> 8, ks = (s >> 6) & 3, gg = (s >> 4) & 3, rr = s & 15;
    pB[it] = z_bf + (size_t)(c0 + j * 16 + rr) * DIM + (ks * 4 + gg) * 8;
  }

#define STAGE_B(buf, tt)                                              \
  {                                                                   \
    gload_lds16(pB[0] + (tt) * 32 * DIM, (buf) + (wave * 64) * 8);    \
    gload_lds16(pB[1] + (tt) * 32 * DIM, (buf) + (256 + wave * 64) * 8); \
  }

  STAGE_B(Bs[0], 0)

  // A fragments: af[i][ks] = A[rb*128 + wave*32 + i*16 + r16][(ks*4+g)*8..+8]
  bf16x8 af[2][4];
  {
    const unsigned short* Ar =
        a_bf + (size_t)(rb * BM + wave * 32 + r16) * DIM + g * 8;
    #pragma unroll
    for (int i = 0; i < 2; ++i)
      #pragma unroll
      for (int ks = 0; ks < 4; ++ks)
        af[i][ks] = *(const bf16x8*)(Ar + i * 16 * DIM + ks * 32);
  }

  float sumt = 0.f, sumab = 0.f, logacc = 0.f, diagsum = 0.f;
  const bool diagblk = (cgi >> 3) == rb;   // block col-owner range hits rows
  const int cbase = c0 >> 4;               // owner-anchor base of col range
  const int rbase = rb * BM + wave * 32 + g * 4;

  #pragma unroll 1
  for (int tt = 0; tt < NT; ++tt) {
    if (tt + 1 < NT) {
      STAGE_B(Bs[(tt + 1) & 1], tt + 1)
      asm volatile("s_waitcnt vmcnt(2)" ::: "memory");
    } else {
      asm volatile("s_waitcnt vmcnt(0)" ::: "memory");
    }
    __builtin_amdgcn_s_barrier();
    asm volatile("" ::: "memory");

    const unsigned short* Bb = Bs[tt & 1];

    f32x4 acc[2][2];
    #pragma unroll
    for (int i = 0; i < 2; ++i) { acc[i][0] = 0.f; acc[i][1] = 0.f; }

    #pragma unroll
    for (int ks = 0; ks < 4; ++ks) {
      bf16x8 b0 = *(const bf16x8*)(Bb + (ks * 64 + lane) * 8);
      bf16x8 b1 = *(const bf16x8*)(Bb + ((4 + ks) * 64 + lane) * 8);
      #pragma unroll
      for (int i = 0; i < 2; ++i) {
        acc[i][0] = __builtin_amdgcn_mfma_f32_16x16x32_bf16(af[i][ks], b0,
                                                            acc[i][0], 0, 0, 0);
        acc[i][1] = __builtin_amdgcn_mfma_f32_16x16x32_bf16(af[i][ks], b1,
                                                            acc[i][1], 0, 0, 0);
      }
    }

    // epilogue: 3 VALU + 1 trans per element (t-units; *LN2 at the end)
    float st[4]  = {0.f, 0.f, 0.f, 0.f};
    float sab[4] = {0.f, 0.f, 0.f, 0.f};
    float pr[4]  = {1.f, 1.f, 1.f, 1.f};
    #pragma unroll
    for (int i = 0; i < 2; ++i)
      #pragma unroll
      for (int j = 0; j < 2; ++j)
        #pragma unroll
        for (int r = 0; r < 4; ++r) {
          float tv = acc[i][j][r];
          st[r]  += tv;
          sab[r] += fabsf(tv);
          pr[r] = fmaf(pr[r], __builtin_amdgcn_exp2f(-fabsf(tv)), pr[r]);
        }
    sumt  += (st[0] + st[1]) + (st[2] + st[3]);
    sumab += (sab[0] + sab[1]) + (sab[2] + sab[3]);
    // <=4 factors in [1,2] per pr => product bounded: safe; one log per tile
    logacc += __builtin_amdgcn_logf((pr[0] * pr[1]) * (pr[2] * pr[3]));

    if (diagblk) {
      #pragma unroll
      for (int j = 0; j < 2; ++j) {
        int o = cbase + tt * 2 + j;          // owner anchor of col group j
        #pragma unroll
        for (int i = 0; i < 2; ++i)
          #pragma unroll
          for (int r = 0; r < 4; ++r)
            diagsum += (rbase + i * 16 + r == o) ? acc[i][j][r] : 0.f;
      }
    }

    asm volatile("s_waitcnt lgkmcnt(0)" ::: "memory");
    __builtin_amdgcn_s_barrier();
    asm volatile("" ::: "memory");
  }

  float local = 0.5f * (sumt + sumab) + logacc - diagsum;
  #pragma unroll
  for (int o = 32; o >= 1; o >>= 1) local += __shfl_xor(local, o);
  if (lane == 0) red[wave] = local;
  __syncthreads();

  if (t == 0) {
    float bsum = (red[0] + red[1]) + (red[2] + red[3]);
    __hip_atomic_store(&partial[bid], bsum, __ATOMIC_RELEASE,
                       __HIP_MEMORY_SCOPE_AGENT);
    unsigned prev = __hip_atomic_fetch_add(counter, 1u, __ATOMIC_ACQ_REL,
                                           __HIP_MEMORY_SCOPE_AGENT);
    lastflag = (prev == NBLK - 1);
  }
  __syncthreads();

  if (lastflag) {   // last block: deterministic fixed-order final reduction
    float s = 0.f;
    for (int i = t; i < NBLK; i += 256)
      s += __hip_atomic_load(&partial[i], __ATOMIC_RELAXED,
                             __HIP_MEMORY_SCOPE_AGENT);
    #pragma unroll
    for (int o = 32; o >= 1; o >>= 1) s += __shfl_xor(s, o);
    if (lane == 0) red[wave] = s;
    __syncthreads();
    if (t == 0)
      out[0] = ((red[0] + red[1]) + (red[2] + red[3])) * (LN2 / TOTAL_ELEMS);
  }
}

extern "C" void kernel_launch(void* const* d_in, const int* in_sizes, int n_in,
                              void* d_out, int out_size, void* d_ws, size_t ws_size,
                              hipStream_t stream) {
  const float* anchor = (const float*)d_in[0];
  const float* pos    = (const float*)d_in[1];
  const float* neg    = (const float*)d_in[2];
  char* ws = (char*)d_ws;
  unsigned short* a_bf = (unsigned short*)ws;                    // 512 KB
  unsigned short* z_bf = (unsigned short*)(ws + 524288);         // 8 MB
  float* partial       = (float*)(ws + 524288 + 8388608);        // 8 KB
  unsigned* counter    = (unsigned*)(ws + 524288 + 8388608 + 16384);

  hipMemsetAsync(counter, 0, sizeof(unsigned), stream);
  norm_kernel<<<dim3(NROWS / 8), dim3(256), 0, stream>>>(
      anchor, pos, neg, a_bf, z_bf);
  gemm_loss_kernel<<<dim3(NBLK), dim3(256), 0, stream>>>(
      a_bf, z_bf, partial, counter, (float*)d_out);
}

// Round 7
// 49.727 us; speedup vs baseline: 1.8312x; 1.8312x over previous
//
#include <hip/hip_runtime.h>
#include <stdint.h>

// Problem constants
#define N_ANCHOR 2048
#define DIM 128
#define NEG_PER 15
#define NZ 32768                    // 2048*16 candidate rows
#define NROWS (N_ANCHOR + NZ)       // 34816
#define INV_TEMP 3.3333333333333335f
#define LOG2E 1.4426950408889634f
#define LN2 0.6931471805599453f
#define TOTAL_ELEMS 67108864.0f
#define A_PRESCALE (INV_TEMP * LOG2E)   // folded into anchor normalization

#define BM 256                      // rows per block (4 waves x 64: 2 row-blocks of 32)
#define CPB 256                     // cols per block
#define NT (CPB / 32)               // 8 B-tiles of 32 cols
#define RB (N_ANCHOR / BM)          // 8
#define CG (NZ / CPB)               // 128
#define NBLK (RB * CG)              // 1024 -> 4 blocks/CU

using bf16x8 = __attribute__((ext_vector_type(8))) __bf16;
using f32x16 = __attribute__((ext_vector_type(16))) float;

// ---------- helpers ----------
static __device__ __forceinline__ unsigned short f2bf(float f) {
  union { float f; unsigned u; } v; v.f = f;
  unsigned r = v.u + 0x7FFF + ((v.u >> 16) & 1);   // round-to-nearest-even
  return (unsigned short)(r >> 16);
}

static __device__ __forceinline__ float bf2f(unsigned short u) {
  union { unsigned u; float f; } v; v.u = ((unsigned)u) << 16;
  return v.f;
}

static __device__ __forceinline__ void gload_lds16(const void* g, void* l) {
  __builtin_amdgcn_global_load_lds(
      (const __attribute__((address_space(1))) void*)g,
      (__attribute__((address_space(3))) void*)l, 16, 0, 0);
}

// ---------- kernel 1: L2-normalize rows, cast to bf16 ----------
__global__ __launch_bounds__(256) void norm_kernel(
    const float* __restrict__ anchor, const float* __restrict__ pos,
    const float* __restrict__ neg, unsigned short* __restrict__ a_bf,
    unsigned short* __restrict__ z_bf) {
  int row = blockIdx.x * 8 + (threadIdx.x >> 5);
  int l32 = threadIdx.x & 31;
  const float* src;
  unsigned short* dst;
  float pre;
  if (row < N_ANCHOR) {
    src = anchor + row * DIM;
    dst = a_bf + row * DIM;
    pre = A_PRESCALE;
  } else {
    int rz = row - N_ANCHOR;
    int j = rz >> 4, k = rz & 15;
    src = (k == 0) ? (pos + j * DIM) : (neg + (j * NEG_PER + (k - 1)) * DIM);
    dst = z_bf + rz * DIM;
    pre = 1.0f;
  }
  float4 v = ((const float4*)src)[l32];
  float s = v.x * v.x + v.y * v.y + v.z * v.z + v.w * v.w;
  #pragma unroll
  for (int o = 16; o >= 1; o >>= 1) s += __shfl_xor(s, o, 32);
  float scale = pre / fmaxf(sqrtf(s), 1e-12f);
  ushort4 o4;
  o4.x = f2bf(v.x * scale); o4.y = f2bf(v.y * scale);
  o4.z = f2bf(v.z * scale); o4.w = f2bf(v.w * scale);
  ((ushort4*)dst)[l32] = o4;
}

// ---------- kernel 2: closed-form diagonal ----------
// dpart[i] = <a'_i, sum_k z_{ik}>  (t-units, since a' is prescaled)
// One wave per anchor; lane owns dims 2*lane, 2*lane+1.
__global__ __launch_bounds__(256) void diag_kernel(
    const unsigned short* __restrict__ a_bf,
    const unsigned short* __restrict__ z_bf, float* __restrict__ dpart) {
  int i    = blockIdx.x * 4 + (threadIdx.x >> 6);
  int lane = threadIdx.x & 63;
  ushort2 a2 = *(const ushort2*)(a_bf + i * DIM + lane * 2);
  float s0 = 0.f, s1 = 0.f;
  const unsigned short* zr = z_bf + (size_t)i * 16 * DIM + lane * 2;
  #pragma unroll
  for (int k = 0; k < 16; ++k) {
    ushort2 z2 = *(const ushort2*)(zr + k * DIM);
    s0 += bf2f(z2.x);
    s1 += bf2f(z2.y);
  }
  float d = bf2f(a2.x) * s0 + bf2f(a2.y) * s1;
  #pragma unroll
  for (int o = 32; o >= 1; o >>= 1) d += __shfl_xor(d, o);
  if (lane == 0) dpart[i] = d;
}

// ---------- kernel 3: fused GEMM + loss (no positional logic) ----------
// 32x32x16 bf16 MFMA; A stripe in regs (af[2][8], 64 VGPR); B 32-col tiles
// double-buffered 2x8KB LDS, fragment order; counted vmcnt(2) pipeline.
// Epilogue is position-independent (diagonal handled by diag_kernel), so any
// consistent A/B lane mapping is sum-invariant.
__global__ __launch_bounds__(256) void gemm_loss_kernel(
    const unsigned short* __restrict__ a_bf,
    const unsigned short* __restrict__ z_bf,
    float* __restrict__ partial) {
  __shared__ __align__(16) unsigned short Bs[2][512 * 8];   // 2 x 8 KB
  __shared__ float red[4];

  const int t    = threadIdx.x;
  const int bid  = blockIdx.x;
  const int rb   = bid >> 7;       // 8 row-blocks of 256
  const int cgi  = bid & 127;      // 128 col-groups of 256
  const int wave = t >> 6;
  const int lane = t & 63;
  const int c0   = cgi * CPB;

  // B stage (fragment order for 32x32x16): LDS slot s = it*256 + t holds
  // z[col = c0 + tile*32 + (s&31)][k = (s>>6)*16 + ((s>>5)&1)*8 .. +8]
  // slot s and s+256 differ only by ks+=4 -> +64 shorts (uniform delta).
  const unsigned short* pB0 =
      z_bf + (size_t)(c0 + (lane & 31)) * DIM + (t >> 6 /*==wave: ks low*/) * 0;
  // build explicitly to avoid confusion:
  const unsigned short* pB;
  {
    int s = t;                      // slot for it=0
    int ks = s >> 6, col = s & 31, khalf = (s >> 5) & 1;
    pB = z_bf + (size_t)(c0 + col) * DIM + ks * 16 + khalf * 8;
  }

#define STAGE_B(buf, tt)                                                   \
  {                                                                        \
    const unsigned short* bg = pB + (size_t)(tt) * 32 * DIM;               \
    gload_lds16(bg, (buf) + (wave * 64) * 8);                              \
    gload_lds16(bg + 64, (buf) + (256 + wave * 64) * 8);                   \
  }

  STAGE_B(Bs[0], 0)

  // A fragments: af[i2][ks] = a[rb*256 + wave*64 + i2*32 + (lane&31)]
  //                             [k = ks*16 + (lane>>5)*8 .. +8]
  bf16x8 af[2][8];
  {
    const unsigned short* Ar =
        a_bf + (size_t)(rb * BM + wave * 64 + (lane & 31)) * DIM +
        (lane >> 5) * 8;
    #pragma unroll
    for (int i = 0; i < 2; ++i)
      #pragma unroll
      for (int ks = 0; ks < 8; ++ks)
        af[i][ks] = *(const bf16x8*)(Ar + i * 32 * DIM + ks * 16);
  }

  STAGE_B(Bs[1], 1)

  float sumt = 0.f, sumab = 0.f, logacc = 0.f;

  #pragma unroll 1
  for (int tt = 0; tt < NT; ++tt) {
    if (tt + 1 < NT) {
      STAGE_B(Bs[(tt + 1) & 1], tt + 1)
      asm volatile("s_waitcnt vmcnt(2)" ::: "memory");
    } else {
      asm volatile("s_waitcnt vmcnt(0)" ::: "memory");
    }
    __builtin_amdgcn_s_barrier();
    asm volatile("" ::: "memory");

    const unsigned short* Bb = Bs[tt & 1];

    f32x16 acc0, acc1;
    acc0 = 0.0f; acc1 = 0.0f;

    #pragma unroll
    for (int ks = 0; ks < 8; ++ks) {
      bf16x8 b = *(const bf16x8*)(Bb + (ks * 64 + lane) * 8);
      acc0 = __builtin_amdgcn_mfma_f32_32x32x16_bf16(af[0][ks], b, acc0, 0, 0, 0);
      acc1 = __builtin_amdgcn_mfma_f32_32x32x16_bf16(af[1][ks], b, acc1, 0, 0, 0);
    }

    // epilogue: per element add + add(|.|) + exp2 + fma; 4 indep chains
    float st[4]  = {0.f, 0.f, 0.f, 0.f};
    float sab[4] = {0.f, 0.f, 0.f, 0.f};
    float pr[4]  = {1.f, 1.f, 1.f, 1.f};
    #pragma unroll
    for (int e = 0; e < 16; ++e) {
      float tv = acc0[e];
      int r = e & 3;
      st[r]  += tv;
      sab[r] += fabsf(tv);
      pr[r] = fmaf(pr[r], __builtin_amdgcn_exp2f(-fabsf(tv)), pr[r]);
    }
    #pragma unroll
    for (int e = 0; e < 16; ++e) {
      float tv = acc1[e];
      int r = e & 3;
      st[r]  += tv;
      sab[r] += fabsf(tv);
      pr[r] = fmaf(pr[r], __builtin_amdgcn_exp2f(-fabsf(tv)), pr[r]);
    }
    sumt  += (st[0] + st[1]) + (st[2] + st[3]);
    sumab += (sab[0] + sab[1]) + (sab[2] + sab[3]);
    // 8 factors in [1,2] per chain -> product <= 2^32: safe
    logacc += __builtin_amdgcn_logf((pr[0] * pr[1]) * (pr[2] * pr[3]));

    asm volatile("s_waitcnt lgkmcnt(0)" ::: "memory");
    __builtin_amdgcn_s_barrier();
    asm volatile("" ::: "memory");
  }

  float local = 0.5f * (sumt + sumab) + logacc;
  #pragma unroll
  for (int o = 32; o >= 1; o >>= 1) local += __shfl_xor(local, o);
  if (lane == 0) red[wave] = local;
  __syncthreads();
  if (t == 0) partial[bid] = (red[0] + red[1]) + (red[2] + red[3]);
}

// ---------- kernel 4: final reduction ----------
// out = LN2/N * (sum(partial) - sum(dpart))
__global__ __launch_bounds__(256) void reduce_kernel(
    const float* __restrict__ partial, const float* __restrict__ dpart,
    float* __restrict__ out) {
  int t = threadIdx.x;
  float s = 0.0f;
  for (int i = t; i < NBLK; i += 256) s += partial[i];
  for (int i = t; i < N_ANCHOR; i += 256) s -= dpart[i];
  #pragma unroll
  for (int o = 32; o >= 1; o >>= 1) s += __shfl_xor(s, o);
  __shared__ float red[4];
  if ((t & 63) == 0) red[t >> 6] = s;
  __syncthreads();
  if (t == 0)
    out[0] = ((red[0] + red[1]) + (red[2] + red[3])) * (LN2 / TOTAL_ELEMS);
}

extern "C" void kernel_launch(void* const* d_in, const int* in_sizes, int n_in,
                              void* d_out, int out_size, void* d_ws, size_t ws_size,
                              hipStream_t stream) {
  const float* anchor = (const float*)d_in[0];
  const float* pos    = (const float*)d_in[1];
  const float* neg    = (const float*)d_in[2];
  char* ws = (char*)d_ws;
  unsigned short* a_bf = (unsigned short*)ws;                    // 512 KB
  unsigned short* z_bf = (unsigned short*)(ws + 524288);         // 8 MB
  float* partial       = (float*)(ws + 524288 + 8388608);        // 4 KB
  float* dpart         = (float*)(ws + 524288 + 8388608 + 4096); // 8 KB

  norm_kernel<<<dim3(NROWS / 8), dim3(256), 0, stream>>>(
      anchor, pos, neg, a_bf, z_bf);
  diag_kernel<<<dim3(N_ANCHOR / 4), dim3(256), 0, stream>>>(a_bf, z_bf, dpart);
  gemm_loss_kernel<<<dim3(NBLK), dim3(256), 0, stream>>>(a_bf, z_bf, partial);
  reduce_kernel<<<dim3(1), dim3(256), 0, stream>>>(partial, dpart,
                                                   (float*)d_out);
}